// Round 1
// baseline (89.797 us; speedup 1.0000x reference)
//
#include <hip/hip_runtime.h>

constexpr int DEPTH      = 10;
constexpr int NUM_TREES  = 64;
constexpr int BATCH      = 2048;
constexpr int NUM_FORKS  = (1 << DEPTH) - 1;   // 1023
constexpr int PAIRS      = BATCH * NUM_TREES;  // 131072
constexpr int WPB        = 4;                  // waves per block
constexpr int REGION     = 1056;               // dword stride per wave LDS region

__device__ __forceinline__ float sig(float v) {
    // fast sigmoid: 1/(1+exp(-v)); exp->v_exp_f32, rcp->v_rcp_f32
    return __builtin_amdgcn_rcpf(1.0f + __expf(-v));
}

__global__ __launch_bounds__(256, 4) void ndt_kernel(const float* __restrict__ x,
                                                     float* __restrict__ out) {
    __shared__ float lds[WPB * REGION + 8];
    const int tid  = threadIdx.x;
    const int wave = tid >> 6;
    const int lane = tid & 63;
    const int pair = blockIdx.x * WPB + wave;          // pair = b*64 + t
    const float* __restrict__ xp = x + (size_t)pair * NUM_FORKS;

    // s[q] = x[q-1]; absolute index wave*1056+4+q so that s[512+8*lane] is
    // 16B-aligned (level-9 ds_read_b128) and s[256+4*lane] likewise.
    float* s = &lds[wave * REGION + 4];

    // stage 1023 floats, coalesced b32, stride-1 LDS writes (conflict-free)
    #pragma unroll
    for (int m = 0; m < 16; ++m) {
        int f = m * 64 + lane;
        if (m < 15 || f < NUM_FORKS) s[1 + f] = xp[f];
    }
    __syncthreads();   // cross-lane LDS visibility within the wave (safe form)

    // ---- level 9: leaf sigmoids (8 per lane, 2x ds_read_b128) ----
    float t9[8];
    #pragma unroll
    for (int c = 0; c < 8; ++c) t9[c] = sig(s[512 + 8 * lane + c]);

    // ---- level 8: v8[d] = (1-s)*t9[2d] + s*t9[2d+1] ----
    float v8[4];
    #pragma unroll
    for (int d = 0; d < 4; ++d) {
        float sg = sig(s[256 + 4 * lane + d]);
        v8[d] = fmaf(sg, t9[2 * d + 1] - t9[2 * d], t9[2 * d]);
    }

    // ---- level 7 ----
    float v7[2];
    #pragma unroll
    for (int e = 0; e < 2; ++e) {
        float sg = sig(s[128 + 2 * lane + e]);
        v7[e] = fmaf(sg, v8[2 * e + 1] - v8[2 * e], v8[2 * e]);
    }

    // ---- level 6 ----
    float s6 = sig(s[64 + lane]);
    float v6 = fmaf(s6, v7[1] - v7[0], v7[0]);

    // ---- path prefix over levels 0..5 (broadcast-friendly reads) ----
    float prefix = 1.0f;
    #pragma unroll
    for (int i = 0; i < 6; ++i) {
        int a = lane >> (6 - i);          // ancestor index at level i
        int b = (lane >> (5 - i)) & 1;    // child bit taken at level i
        float sg = sig(s[(1 << i) + a]);
        prefix *= b ? sg : (1.0f - sg);
    }

    // ---- combine + wave-wide sum ----
    float v = prefix * v6;
    #pragma unroll
    for (int off = 32; off > 0; off >>= 1) v += __shfl_xor(v, off, 64);
    if (lane == 0) out[pair] = v;
}

extern "C" void kernel_launch(void* const* d_in, const int* in_sizes, int n_in,
                              void* d_out, int out_size, void* d_ws, size_t ws_size,
                              hipStream_t stream) {
    const float* x = (const float*)d_in[0];
    float* out = (float*)d_out;
    dim3 grid(PAIRS / WPB), block(WPB * 64);
    ndt_kernel<<<grid, block, 0, stream>>>(x, out);
}